// Round 11
// baseline (87.306 us; speedup 1.0000x reference)
//
#include <hip/hip_runtime.h>

// 3D trilinear warp (grid_sample, align_corners=True equivalent, zeros padding)
// src:  [B=2, C=1, D=160, H=192, W=224] f32
// flow: [B=2, 3,   D,     H,     W    ] f32  (d,h,w voxel displacements)
// out:  [B=2, C=1, D,     H,     W    ] f32
//
// LDS-staged gathers, bf16 PAIR-PACKED tile: dword j of a row holds
// (bf16(v[j]), bf16(v[j+1])) so each (d,h) corner's w-pair is ONE b32 read.
// Bank accesses/voxel: 4 (was 8); conflicts halve. Brick = 16d x 8h x 16w
// (R9 winner: 4 blocks/CU for cross-block staging/compute overlap), halo 4.
// Region 24x16 rows x 23 pair-dwords = 35.3 KB LDS.

#define DD 160
#define HH 192
#define WW 224
constexpr int DHW = DD * HH * WW;          // 6,881,280
constexpr int BLOCK = 512;
// Brick: 16d x 8h x 16w.
constexpr int DT = DD / 16;                // 10
constexpr int HT = HH / 8;                 // 24
constexpr int WT = WW / 16;                // 14
constexpr int BRICKS_PER_B = DT * HT * WT; // 3360
constexpr int NWG = 2 * BRICKS_PER_B;      // 6720, divisible by 8
constexpr int NXCD = 8;
constexpr int CHUNK = NWG / NXCD;          // 840

// Staged region: halo 4 each side. d: 24; h: 16; w floats: 24 -> 23 pair-dwords.
constexpr int RD = 24, RH = 16, RWE = 24;
constexpr int PW = 23;                     // pair-dwords per row
constexpr int SROWS = RD * RH;             // 384 rows
constexpr int TILE_N = SROWS * PW;         // 8832 dwords = 35.3 KB
constexpr int DROW = RH * PW;              // d-stride in dwords (368)

typedef float vfloat4 __attribute__((ext_vector_type(4)));

// bf16 pair pack/unpack (round-half-up; error <= 2^-9 relative).
__device__ __forceinline__ unsigned packpair(float a, float b) {
    unsigned ua = __float_as_uint(a) + 0x8000u;
    unsigned ub = __float_as_uint(b) + 0x8000u;
    return (ua >> 16) | (ub & 0xFFFF0000u);
}
__device__ __forceinline__ float plo(unsigned u) {
    return __uint_as_float(u << 16);
}
__device__ __forceinline__ float phi(unsigned u) {
    return __uint_as_float(u & 0xFFFF0000u);
}

// Global fallback tap (rare, beyond-halo): exact f32, branchless, clamped,
// validity folded into weights.
__device__ __forceinline__ float trilerp_global(const float* __restrict__ sbase,
                                                float cd, float ch, float cw) {
    float d0f = floorf(cd), h0f = floorf(ch), w0f = floorf(cw);
    float fd = cd - d0f, fh = ch - h0f, fw = cw - w0f;
    int d0 = (int)d0f, h0 = (int)h0f, w0 = (int)w0f;
    int d1 = d0 + 1, h1 = h0 + 1, w1 = w0 + 1;

    float wd0 = (1.0f - fd) * ((unsigned)d0 < (unsigned)DD ? 1.0f : 0.0f);
    float wd1 = fd          * ((unsigned)d1 < (unsigned)DD ? 1.0f : 0.0f);
    float wh0 = (1.0f - fh) * ((unsigned)h0 < (unsigned)HH ? 1.0f : 0.0f);
    float wh1 = fh          * ((unsigned)h1 < (unsigned)HH ? 1.0f : 0.0f);
    float ww0 = (1.0f - fw) * ((unsigned)w0 < (unsigned)WW ? 1.0f : 0.0f);
    float ww1 = fw          * ((unsigned)w1 < (unsigned)WW ? 1.0f : 0.0f);

    int d0c = min(max(d0, 0), DD - 1), d1c = min(max(d1, 0), DD - 1);
    int h0c = min(max(h0, 0), HH - 1), h1c = min(max(h1, 0), HH - 1);
    int w0c = min(max(w0, 0), WW - 1), w1c = min(max(w1, 0), WW - 1);

    const float* p00 = sbase + (d0c * HH + h0c) * WW;
    const float* p01 = sbase + (d0c * HH + h1c) * WW;
    const float* p10 = sbase + (d1c * HH + h0c) * WW;
    const float* p11 = sbase + (d1c * HH + h1c) * WW;

    return wd0 * (wh0 * (ww0 * p00[w0c] + ww1 * p00[w1c]) +
                  wh1 * (ww0 * p01[w0c] + ww1 * p01[w1c])) +
           wd1 * (wh0 * (ww0 * p10[w0c] + ww1 * p10[w1c]) +
                  wh1 * (ww0 * p11[w0c] + ww1 * p11[w1c]));
}

__global__ __launch_bounds__(512, 8) void warp3d_kernel(
    const float* __restrict__ src, const float* __restrict__ flow,
    float* __restrict__ out) {
    __shared__ unsigned tile[TILE_N];

    // XCD-aware swizzle: contiguous brick ranges per XCD.
    int bid = blockIdx.x;
    int wg  = (bid & 7) * CHUNK + (bid >> 3);

    int b  = wg / BRICKS_PER_B;
    int r  = wg - b * BRICKS_PER_B;
    int dt = r / (HT * WT);
    int r2 = r - dt * (HT * WT);
    int ht = r2 / WT;
    int wtile = r2 - ht * WT;

    int dB = dt * 16, hB = ht * 8, wB = wtile * 16;
    int dB4 = dB - 4, hB4 = hB - 4, wB4 = wB - 4;

    // Region strictly inside the volume -> no validity masks needed.
    bool interior = (dt >= 1) & (dt <= DT - 2) & (ht >= 1) & (ht <= HT - 2)
                  & (wtile >= 1) & (wtile <= WT - 2);

    const float* sbase = src + (size_t)b * DHW;

    // Output voxel mapping (wave = 4d x 4h x 16w sub-brick; 8 waves = 16x8).
    int tid  = threadIdx.x;
    int wave = tid >> 6;
    int lane = tid & 63;
    int d = dB + (wave >> 1) * 4 + (lane >> 4);
    int h = hB + (wave & 1) * 4 + ((lane >> 2) & 3);
    int w = wB + (lane & 3) * 4;

    size_t sOff = (size_t)(d * HH + h) * WW + w;
    const float* fb = flow + (size_t)b * 3 * DHW + sOff;
    // Issue flow loads first; they drain while staging proceeds.
    vfloat4 fld = *reinterpret_cast<const vfloat4*>(fb);
    vfloat4 flh = *reinterpret_cast<const vfloat4*>(fb + DHW);
    vfloat4 flw = *reinterpret_cast<const vfloat4*>(fb + 2 * DHW);

    // ---- Stage src region into LDS as bf16 pairs ----
    // 384 rows; chunk c<5: pair-dwords 4c..4c+3 from floats 4c..4c+4;
    // chunk c=5: pair-dwords 20..22 from floats 20..23.
    bool wedge = (wtile == 0) | (wtile == WT - 1);  // w-halo crosses volume
    for (int u = tid; u < SROWS * 6; u += BLOCK) {
        int row = u / 6;                   // 0..383
        int c   = u - row * 6;             // 0..5
        int ld = row >> 4, lh = row & 15;
        int dg = min(max(dB4 + ld, 0), DD - 1);
        int hg = min(max(hB4 + lh, 0), HH - 1);
        const float* grow = sbase + (size_t)(dg * HH + hg) * WW;
        int wg0 = wB4 + 4 * c;             // 16B-aligned for interior tiles
        float v0, v1, v2, v3, v4;
        if (!wedge) {
            vfloat4 q = *reinterpret_cast<const vfloat4*>(grow + wg0);
            v0 = q.x; v1 = q.y; v2 = q.z; v3 = q.w;
            v4 = (c < 5) ? grow[wg0 + 4] : 0.0f;
        } else {
            v0 = grow[min(max(wg0 + 0, 0), WW - 1)];
            v1 = grow[min(max(wg0 + 1, 0), WW - 1)];
            v2 = grow[min(max(wg0 + 2, 0), WW - 1)];
            v3 = grow[min(max(wg0 + 3, 0), WW - 1)];
            v4 = grow[min(max(wg0 + 4, 0), WW - 1)];
        }
        unsigned* dst = &tile[row * PW + 4 * c];
        dst[0] = packpair(v0, v1);
        dst[1] = packpair(v1, v2);
        dst[2] = packpair(v2, v3);
        if (c < 5) dst[3] = packpair(v3, v4);
    }
    __syncthreads();

    float df = (float)d, hf = (float)h, wf = (float)w;
    float fdv[4] = {fld.x, fld.y, fld.z, fld.w};
    float fhv[4] = {flh.x, flh.y, flh.z, flh.w};
    float fwv[4] = {flw.x, flw.y, flw.z, flw.w};

    float cdv[4], chv[4], cwv[4];
    float fdq[4], fhq[4], fwq[4];
    int   base[4];
    bool  okv[4];
    #pragma unroll
    for (int k = 0; k < 4; ++k) {
        float cd = df + fdv[k], ch = hf + fhv[k], cw = wf + (float)k + fwv[k];
        cdv[k] = cd; chv[k] = ch; cwv[k] = cw;
        float d0f = floorf(cd), h0f = floorf(ch), w0f = floorf(cw);
        fdq[k] = cd - d0f; fhq[k] = ch - h0f; fwq[k] = cw - w0f;
        int rd = (int)d0f - dB4, rh = (int)h0f - hB4, rw = (int)w0f - wB4;
        okv[k] = ((unsigned)rd < (unsigned)(RD - 1)) &
                 ((unsigned)rh < (unsigned)(RH - 1)) &
                 ((unsigned)rw < (unsigned)(RWE - 1));
        base[k] = (rd * RH + rh) * PW + rw;
    }
    bool allin = okv[0] & okv[1] & okv[2] & okv[3];

    float res[4];
    if (allin) {
        if (interior) {
            // 4 b32 LDS taps (pair-packed) + lerp tree per voxel.
            #pragma unroll
            for (int k = 0; k < 4; ++k) {
                int b0 = base[k];
                float fw = fwq[k], fh = fhq[k], fd = fdq[k];
                unsigned u0 = tile[b0];
                unsigned u1 = tile[b0 + PW];
                unsigned u2 = tile[b0 + DROW];
                unsigned u3 = tile[b0 + DROW + PW];
                float a0 = plo(u0), a1 = phi(u0);
                float b1 = plo(u1), b2 = phi(u1);
                float c0 = plo(u2), c1 = phi(u2);
                float e0 = plo(u3), e1 = phi(u3);
                float x0 = fmaf(fw, a1 - a0, a0);
                float x1 = fmaf(fw, b2 - b1, b1);
                float x2 = fmaf(fw, c1 - c0, c0);
                float x3 = fmaf(fw, e1 - e0, e0);
                float y0 = fmaf(fh, x1 - x0, x0);
                float y1 = fmaf(fh, x3 - x2, x2);
                res[k] = fmaf(fd, y1 - y0, y0);
            }
        } else {
            // Edge block: validity folded into weights (zeros padding).
            #pragma unroll
            for (int k = 0; k < 4; ++k) {
                int d0 = (int)floorf(cdv[k]), h0 = (int)floorf(chv[k]),
                    w0 = (int)floorf(cwv[k]);
                float fd = fdq[k], fh = fhq[k], fw = fwq[k];
                float wd0 = (1.0f - fd) * ((unsigned)d0 < (unsigned)DD ? 1.0f : 0.0f);
                float wd1 = fd    * ((unsigned)(d0 + 1) < (unsigned)DD ? 1.0f : 0.0f);
                float wh0 = (1.0f - fh) * ((unsigned)h0 < (unsigned)HH ? 1.0f : 0.0f);
                float wh1 = fh    * ((unsigned)(h0 + 1) < (unsigned)HH ? 1.0f : 0.0f);
                float ww0 = (1.0f - fw) * ((unsigned)w0 < (unsigned)WW ? 1.0f : 0.0f);
                float ww1 = fw    * ((unsigned)(w0 + 1) < (unsigned)WW ? 1.0f : 0.0f);
                int b0 = base[k];
                unsigned u0 = tile[b0];
                unsigned u1 = tile[b0 + PW];
                unsigned u2 = tile[b0 + DROW];
                unsigned u3 = tile[b0 + DROW + PW];
                float a = wd0 * wh0, bq = wd0 * wh1, cq = wd1 * wh0, dq = wd1 * wh1;
                res[k] = a  * (ww0 * plo(u0) + ww1 * phi(u0)) +
                         bq * (ww0 * plo(u1) + ww1 * phi(u1)) +
                         cq * (ww0 * plo(u2) + ww1 * phi(u2)) +
                         dq * (ww0 * plo(u3) + ww1 * phi(u3));
            }
        }
    } else {
        // Rare (flow beyond halo): recompute fully from global (exact f32).
        #pragma unroll
        for (int k = 0; k < 4; ++k)
            res[k] = trilerp_global(sbase, cdv[k], chv[k], cwv[k]);
    }

    vfloat4 o4 = {res[0], res[1], res[2], res[3]};
    *reinterpret_cast<vfloat4*>(out + (size_t)b * DHW + sOff) = o4;
}

extern "C" void kernel_launch(void* const* d_in, const int* in_sizes, int n_in,
                              void* d_out, int out_size, void* d_ws, size_t ws_size,
                              hipStream_t stream) {
    const float* src  = (const float*)d_in[0];
    const float* flow = (const float*)d_in[1];
    float* out = (float*)d_out;

    warp3d_kernel<<<NWG, BLOCK, 0, stream>>>(src, flow, out);
}

// Round 12
// 72.642 us; speedup vs baseline: 1.2019x; 1.2019x over previous
//
#include <hip/hip_runtime.h>

// 3D trilinear warp (grid_sample, align_corners=True equivalent, zeros padding)
// src:  [B=2, C=1, D=160, H=192, W=224] f32
// flow: [B=2, 3,   D,     H,     W    ] f32  (d,h,w voxel displacements)
// out:  [B=2, C=1, D,     H,     W    ] f32
//
// R9 geometry (best: 69.5 us): brick 16d x 8h x 16w, 512 thr, halo 4,
// region 24x16x24 @ stride 25 = 38.4 KB LDS, 4 blocks/CU = 100% occupancy.
// R12 change: software-pipelined staging (T14) — issue ALL 5 staging float4
// loads into registers first (1 exposed latency instead of 5 serialized),
// ds_write under counted vmcnt; flow-dependent prep VALU moved before the
// barrier so post-barrier critical path is just ds_read + lerp.
// (R11 lesson: bf16 pair-packing cut conflicts 37% but de-vectorized staging
// and regressed 26% — staging coalescing dominates LDS read-side savings.)

#define DD 160
#define HH 192
#define WW 224
constexpr int DHW = DD * HH * WW;          // 6,881,280
constexpr int BLOCK = 512;
// Brick: 16d x 8h x 16w.
constexpr int DT = DD / 16;                // 10
constexpr int HT = HH / 8;                 // 24
constexpr int WT = WW / 16;                // 14
constexpr int BRICKS_PER_B = DT * HT * WT; // 3360
constexpr int NWG = 2 * BRICKS_PER_B;      // 6720, divisible by 8
constexpr int NXCD = 8;
constexpr int CHUNK = NWG / NXCD;          // 840

// Staged region: halo 4 each side. d: 24; h: 16; w: 24 floats, pad 25.
constexpr int RD = 24, RH = 16, RWE = 24, RWP = 25;
constexpr int TILE_N = RD * RH * RWP;      // 9600 floats = 38.4 KB
constexpr int SROWS = RD * RH;             // 384 staging rows
constexpr int SCHUNKS = SROWS * 6;         // 2304 float4 chunks (4.5/thread)

typedef float vfloat4 __attribute__((ext_vector_type(4)));

// Global fallback tap (rare, beyond-halo): branchless, clamped, validity
// folded into weights — matches reference clip+valid semantics.
__device__ __forceinline__ float trilerp_global(const float* __restrict__ sbase,
                                                float cd, float ch, float cw) {
    float d0f = floorf(cd), h0f = floorf(ch), w0f = floorf(cw);
    float fd = cd - d0f, fh = ch - h0f, fw = cw - w0f;
    int d0 = (int)d0f, h0 = (int)h0f, w0 = (int)w0f;
    int d1 = d0 + 1, h1 = h0 + 1, w1 = w0 + 1;

    float wd0 = (1.0f - fd) * ((unsigned)d0 < (unsigned)DD ? 1.0f : 0.0f);
    float wd1 = fd          * ((unsigned)d1 < (unsigned)DD ? 1.0f : 0.0f);
    float wh0 = (1.0f - fh) * ((unsigned)h0 < (unsigned)HH ? 1.0f : 0.0f);
    float wh1 = fh          * ((unsigned)h1 < (unsigned)HH ? 1.0f : 0.0f);
    float ww0 = (1.0f - fw) * ((unsigned)w0 < (unsigned)WW ? 1.0f : 0.0f);
    float ww1 = fw          * ((unsigned)w1 < (unsigned)WW ? 1.0f : 0.0f);

    int d0c = min(max(d0, 0), DD - 1), d1c = min(max(d1, 0), DD - 1);
    int h0c = min(max(h0, 0), HH - 1), h1c = min(max(h1, 0), HH - 1);
    int w0c = min(max(w0, 0), WW - 1), w1c = min(max(w1, 0), WW - 1);

    const float* p00 = sbase + (d0c * HH + h0c) * WW;
    const float* p01 = sbase + (d0c * HH + h1c) * WW;
    const float* p10 = sbase + (d1c * HH + h0c) * WW;
    const float* p11 = sbase + (d1c * HH + h1c) * WW;

    return wd0 * (wh0 * (ww0 * p00[w0c] + ww1 * p00[w1c]) +
                  wh1 * (ww0 * p01[w0c] + ww1 * p01[w1c])) +
           wd1 * (wh0 * (ww0 * p10[w0c] + ww1 * p10[w1c]) +
                  wh1 * (ww0 * p11[w0c] + ww1 * p11[w1c]));
}

__global__ __launch_bounds__(512, 8) void warp3d_kernel(
    const float* __restrict__ src, const float* __restrict__ flow,
    float* __restrict__ out) {
    __shared__ float tile[TILE_N];

    // XCD-aware swizzle: contiguous brick ranges per XCD.
    int bid = blockIdx.x;
    int wg  = (bid & 7) * CHUNK + (bid >> 3);

    int b  = wg / BRICKS_PER_B;
    int r  = wg - b * BRICKS_PER_B;
    int dt = r / (HT * WT);
    int r2 = r - dt * (HT * WT);
    int ht = r2 / WT;
    int wtile = r2 - ht * WT;

    int dB = dt * 16, hB = ht * 8, wB = wtile * 16;
    int dB4 = dB - 4, hB4 = hB - 4, wB4 = wB - 4;

    // Region strictly inside the volume -> no validity masks needed.
    bool interior = (dt >= 1) & (dt <= DT - 2) & (ht >= 1) & (ht <= HT - 2)
                  & (wtile >= 1) & (wtile <= WT - 2);

    const float* sbase = src + (size_t)b * DHW;

    // Output voxel mapping (wave = 4d x 4h x 16w sub-brick; 8 waves = 16x8).
    int tid  = threadIdx.x;
    int wave = tid >> 6;
    int lane = tid & 63;
    int d = dB + (wave >> 1) * 4 + (lane >> 4);
    int h = hB + (wave & 1) * 4 + ((lane >> 2) & 3);
    int w = wB + (lane & 3) * 4;

    size_t sOff = (size_t)(d * HH + h) * WW + w;
    const float* fb = flow + (size_t)b * 3 * DHW + sOff;
    // 1) Issue flow loads first (needed by prep, which runs pre-barrier).
    vfloat4 fld = *reinterpret_cast<const vfloat4*>(fb);
    vfloat4 flh = *reinterpret_cast<const vfloat4*>(fb + DHW);
    vfloat4 flw = *reinterpret_cast<const vfloat4*>(fb + 2 * DHW);

    // 2) Issue ALL staging loads into registers (batched, one exposed
    //    latency). 2304 chunks / 512 threads: p<4 all threads, p=4 half.
    bool wedge = (wtile == 0) | (wtile == WT - 1);  // w-halo crosses volume
    vfloat4 vv[5];
    #pragma unroll
    for (int p = 0; p < 5; ++p) {
        int u = tid + p * BLOCK;
        if (u < SCHUNKS) {
            int row = u / 6;               // 0..383
            int c   = u - row * 6;         // 0..5
            int ld = row >> 4, lh = row & 15;
            int dg = min(max(dB4 + ld, 0), DD - 1);
            int hg = min(max(hB4 + lh, 0), HH - 1);
            const float* grow = sbase + (size_t)(dg * HH + hg) * WW;
            int wg0 = wB4 + 4 * c;         // 16B-aligned for interior tiles
            if (!wedge) {
                vv[p] = *reinterpret_cast<const vfloat4*>(grow + wg0);
            } else {
                vv[p].x = grow[min(max(wg0 + 0, 0), WW - 1)];
                vv[p].y = grow[min(max(wg0 + 1, 0), WW - 1)];
                vv[p].z = grow[min(max(wg0 + 2, 0), WW - 1)];
                vv[p].w = grow[min(max(wg0 + 3, 0), WW - 1)];
            }
        }
    }

    // 3) Drain into LDS under counted vmcnt (compiler inserts vmcnt(N)).
    #pragma unroll
    for (int p = 0; p < 5; ++p) {
        int u = tid + p * BLOCK;
        if (u < SCHUNKS) {
            int row = u / 6;
            int c   = u - row * 6;
            float* dst = &tile[row * RWP + 4 * c];  // stride 25: scalar writes
            dst[0] = vv[p].x; dst[1] = vv[p].y;
            dst[2] = vv[p].z; dst[3] = vv[p].w;
        }
    }

    // 4) Flow-dependent prep (pure register math) BEFORE the barrier:
    //    post-barrier critical path is then just ds_read + lerp.
    float df = (float)d, hf = (float)h, wf = (float)w;
    float fdv[4] = {fld.x, fld.y, fld.z, fld.w};
    float fhv[4] = {flh.x, flh.y, flh.z, flh.w};
    float fwv[4] = {flw.x, flw.y, flw.z, flw.w};

    float fdq[4], fhq[4], fwq[4];
    int   base[4];
    bool  okv[4];
    #pragma unroll
    for (int k = 0; k < 4; ++k) {
        float cd = df + fdv[k], ch = hf + fhv[k], cw = wf + (float)k + fwv[k];
        float d0f = floorf(cd), h0f = floorf(ch), w0f = floorf(cw);
        fdq[k] = cd - d0f; fhq[k] = ch - h0f; fwq[k] = cw - w0f;
        int rd = (int)d0f - dB4, rh = (int)h0f - hB4, rw = (int)w0f - wB4;
        okv[k] = ((unsigned)rd < (unsigned)(RD - 1)) &
                 ((unsigned)rh < (unsigned)(RH - 1)) &
                 ((unsigned)rw < (unsigned)(RWE - 1));
        base[k] = (rd * RH + rh) * RWP + rw;
    }
    bool allin = okv[0] & okv[1] & okv[2] & okv[3];

    __syncthreads();

    float res[4];
    if (allin) {
        if (interior) {
            // Mask-free: 8 LDS taps + 7-lerp tree per voxel.
            #pragma unroll
            for (int k = 0; k < 4; ++k) {
                int b0 = base[k];
                float fw = fwq[k], fh = fhq[k], fd = fdq[k];
                float v0 = tile[b0],                 v1 = tile[b0 + 1];
                float v2 = tile[b0 + RWP],           v3 = tile[b0 + RWP + 1];
                float v4 = tile[b0 + RH * RWP],      v5 = tile[b0 + RH * RWP + 1];
                float v6 = tile[b0 + RH * RWP + RWP];
                float v7 = tile[b0 + RH * RWP + RWP + 1];
                float x0 = fmaf(fw, v1 - v0, v0);
                float x1 = fmaf(fw, v3 - v2, v2);
                float x2 = fmaf(fw, v5 - v4, v4);
                float x3 = fmaf(fw, v7 - v6, v6);
                float y0 = fmaf(fh, x1 - x0, x0);
                float y1 = fmaf(fh, x3 - x2, x2);
                res[k] = fmaf(fd, y1 - y0, y0);
            }
        } else {
            // Edge block: validity folded into weights (zeros padding).
            #pragma unroll
            for (int k = 0; k < 4; ++k) {
                float cd = df + fdv[k], ch = hf + fhv[k],
                      cw = wf + (float)k + fwv[k];
                int d0 = (int)floorf(cd), h0 = (int)floorf(ch),
                    w0 = (int)floorf(cw);
                float fd = fdq[k], fh = fhq[k], fw = fwq[k];
                float wd0 = (1.0f - fd) * ((unsigned)d0 < (unsigned)DD ? 1.0f : 0.0f);
                float wd1 = fd    * ((unsigned)(d0 + 1) < (unsigned)DD ? 1.0f : 0.0f);
                float wh0 = (1.0f - fh) * ((unsigned)h0 < (unsigned)HH ? 1.0f : 0.0f);
                float wh1 = fh    * ((unsigned)(h0 + 1) < (unsigned)HH ? 1.0f : 0.0f);
                float ww0 = (1.0f - fw) * ((unsigned)w0 < (unsigned)WW ? 1.0f : 0.0f);
                float ww1 = fw    * ((unsigned)(w0 + 1) < (unsigned)WW ? 1.0f : 0.0f);
                int b0 = base[k];
                float v0 = tile[b0],                 v1 = tile[b0 + 1];
                float v2 = tile[b0 + RWP],           v3 = tile[b0 + RWP + 1];
                float v4 = tile[b0 + RH * RWP],      v5 = tile[b0 + RH * RWP + 1];
                float v6 = tile[b0 + RH * RWP + RWP];
                float v7 = tile[b0 + RH * RWP + RWP + 1];
                float a = wd0 * wh0, bq = wd0 * wh1, cq = wd1 * wh0, dq = wd1 * wh1;
                res[k] = a  * (ww0 * v0 + ww1 * v1) + bq * (ww0 * v2 + ww1 * v3) +
                         cq * (ww0 * v4 + ww1 * v5) + dq * (ww0 * v6 + ww1 * v7);
            }
        }
    } else {
        // Rare (flow beyond halo): recompute fully from global.
        #pragma unroll
        for (int k = 0; k < 4; ++k)
            res[k] = trilerp_global(sbase, df + fdv[k], hf + fhv[k],
                                    wf + (float)k + fwv[k]);
    }

    vfloat4 o4 = {res[0], res[1], res[2], res[3]};
    *reinterpret_cast<vfloat4*>(out + (size_t)b * DHW + sOff) = o4;
}

extern "C" void kernel_launch(void* const* d_in, const int* in_sizes, int n_in,
                              void* d_out, int out_size, void* d_ws, size_t ws_size,
                              hipStream_t stream) {
    const float* src  = (const float*)d_in[0];
    const float* flow = (const float*)d_in[1];
    float* out = (float*)d_out;

    warp3d_kernel<<<NWG, BLOCK, 0, stream>>>(src, flow, out);
}